// Round 1
// baseline (1004.378 us; speedup 1.0000x reference)
//
#include <hip/hip_runtime.h>
#include <hip/hip_bf16.h>
#include <stdint.h>

// Problem constants: B=65536, N=20, C=128, H=4, HD=32, OC=128
#define NROWS 65536

typedef short short8 __attribute__((ext_vector_type(8)));
typedef short shortv4 __attribute__((ext_vector_type(4)));
typedef float f32x4 __attribute__((ext_vector_type(4)));

__device__ __forceinline__ short f2bf(float f) {
  uint32_t u = __float_as_uint(f);
  u += 0x7FFFu + ((u >> 16) & 1u);   // round-to-nearest-even
  return (short)(u >> 16);
}
__device__ __forceinline__ float bf2f(short s) {
  return __uint_as_float(((uint32_t)(uint16_t)s) << 16);
}
__device__ __forceinline__ short8 pk8(float4 a, float4 b) {
  short8 r;
  r[0] = f2bf(a.x); r[1] = f2bf(a.y); r[2] = f2bf(a.z); r[3] = f2bf(a.w);
  r[4] = f2bf(b.x); r[5] = f2bf(b.y); r[6] = f2bf(b.z); r[7] = f2bf(b.w);
  return r;
}

// ---------------------------------------------------------------------------
// K0: weight prep — bf16 casts, Wk transposed (wkt[c][d] = Wk[d][c]) so K1's
// B-fragments are 16B-contiguous loads.
// ---------------------------------------------------------------------------
__global__ __launch_bounds__(256) void k_prep(
    const float* __restrict__ Wq, const float* __restrict__ Wk,
    const float* __restrict__ Wv, const float* __restrict__ Wo,
    const float* __restrict__ Ws1, const float* __restrict__ Ws2,
    short* __restrict__ wq, short* __restrict__ wkt, short* __restrict__ wv,
    short* __restrict__ wo, short* __restrict__ ws1, short* __restrict__ ws2)
{
  int idx = blockIdx.x * 256 + threadIdx.x;
  int stride = gridDim.x * 256;
  for (int i = idx; i < 16384; i += stride) {
    wq[i] = f2bf(Wq[i]);
    wv[i] = f2bf(Wv[i]);
    wo[i] = f2bf(Wo[i]);
    int c = i >> 7, d = i & 127;
    wkt[i] = f2bf(Wk[d * 128 + c]);       // wkt[c*128+d] = Wk[d][c]
  }
  for (int i = idx; i < 4096; i += stride) {
    ws1[i] = f2bf(Ws1[i]);
    ws2[i] = f2bf(Ws2[i]);
  }
}

// ---------------------------------------------------------------------------
// K1: per 16-row tile (1 tile/wave, 4 waves/block):
//   Q = X @ Wq^T + bq          (MFMA, 8 ntiles x 4 ksteps)
//   T_h = Q_h @ Wk_h           (MFMA, K=32, 4 heads x 8 ntiles)
// T[b][h*128+c] = t_h[c] = Wk_h^T q_h, written bf16. bk dropped (softmax-shift
// invariant).  Q goes through per-wave LDS (bf16, stride 136: 2-way-free banks)
// to convert C-layout -> A-layout.
// ---------------------------------------------------------------------------
__global__ __launch_bounds__(256) void k_qt(
    const float* __restrict__ x, const float* __restrict__ bq,
    const short* __restrict__ wq, const short* __restrict__ wkt,
    short* __restrict__ T)
{
  __shared__ short qtile[4][16 * 136];
  const int wid = threadIdx.x >> 6;
  const int lane = threadIdx.x & 63;
  const int g = lane & 15;
  const int q4 = lane >> 4;
  const int r0 = blockIdx.x * 64 + wid * 16;
  short* Q = qtile[wid];

  // A-fragments from x (fp32 -> bf16): A[m=g][k=ks*32+q4*8+j]
  short8 af[4];
#pragma unroll
  for (int ks = 0; ks < 4; ++ks) {
    const float* p = x + (size_t)(r0 + g) * 128 + ks * 32 + q4 * 8;
    af[ks] = pk8(*(const float4*)p, *(const float4*)(p + 4));
  }
  // Q = X @ Wq^T + bq  -> LDS (bf16)
#pragma unroll
  for (int nt = 0; nt < 8; ++nt) {
    f32x4 acc = {0.f, 0.f, 0.f, 0.f};
#pragma unroll
    for (int ks = 0; ks < 4; ++ks) {
      short8 bfr = *(const short8*)(wq + (nt * 16 + g) * 128 + ks * 32 + q4 * 8);
      acc = __builtin_amdgcn_mfma_f32_16x16x32_bf16(af[ks], bfr, acc, 0, 0, 0);
    }
    float bias = bq[nt * 16 + g];
#pragma unroll
    for (int i = 0; i < 4; ++i)
      Q[(q4 * 4 + i) * 136 + nt * 16 + g] = f2bf(acc[i] + bias);
  }
  __syncthreads();

  // T_h = Q_h @ Wk_h  (K=32, single MFMA k-step per (h,nt))
#pragma unroll
  for (int h = 0; h < 4; ++h) {
    short8 a = *(const short8*)(Q + g * 136 + h * 32 + q4 * 8);
#pragma unroll
    for (int nt = 0; nt < 8; ++nt) {
      short8 bfr = *(const short8*)(wkt + (nt * 16 + g) * 128 + h * 32 + q4 * 8);
      f32x4 acc = {0.f, 0.f, 0.f, 0.f};
      acc = __builtin_amdgcn_mfma_f32_16x16x32_bf16(a, bfr, acc, 0, 0, 0);
#pragma unroll
      for (int i = 0; i < 4; ++i)
        T[(size_t)(r0 + q4 * 4 + i) * 512 + h * 128 + nt * 16 + g] = f2bf(acc[i]);
    }
  }
}

// ---------------------------------------------------------------------------
// K2: attention core. One wave per row b. 16-lane group per head h=lane>>4;
// lane g owns c in {4g..4g+3} u {64+4g..64+4g+3} (2-way-free LDS banks).
//   scores[h][n] = t_h . nb[n]           (dot + 4-step butterfly over group)
//   softmax over n (scale 1/sqrt(32) folded into exp2)
//   s_h = sum_n attn[n] * nb[n]          (normalized; bv applied in K3)
// S (bf16) overwrites T in-place — same wave reads T before writing S.
// ---------------------------------------------------------------------------
__global__ __launch_bounds__(256) void k_attn(
    const float* __restrict__ nb, short* __restrict__ TS)
{
  __shared__ float lnb[4][20 * 128];     // 40KB/block -> 4 blocks/CU
  const int wid = threadIdx.x >> 6;
  const int lane = threadIdx.x & 63;
  const int g = lane & 15;
  const int h = lane >> 4;
  const int b = blockIdx.x * 4 + wid;
  float* L = lnb[wid];

  const float* src = nb + (size_t)b * 2560;
#pragma unroll
  for (int it = 0; it < 10; ++it)
    *(float4*)(L + it * 256 + lane * 4) = *(const float4*)(src + it * 256 + lane * 4);

  const short* tp = TS + (size_t)b * 512 + h * 128;
  shortv4 ta = *(const shortv4*)(tp + 4 * g);
  shortv4 tb = *(const shortv4*)(tp + 64 + 4 * g);
  float t0[4], t1[4];
#pragma unroll
  for (int j = 0; j < 4; ++j) { t0[j] = bf2f(ta[j]); t1[j] = bf2f(tb[j]); }
  __syncthreads();

  float sc[20];
#pragma unroll
  for (int n = 0; n < 20; ++n) {
    const float* r = L + n * 128 + 4 * g;
    float4 a0 = *(const float4*)r;
    float4 a1 = *(const float4*)(r + 64);
    float p = t0[0]*a0.x + t0[1]*a0.y + t0[2]*a0.z + t0[3]*a0.w
            + t1[0]*a1.x + t1[1]*a1.y + t1[2]*a1.z + t1[3]*a1.w;
    p += __shfl_xor(p, 1);
    p += __shfl_xor(p, 2);
    p += __shfl_xor(p, 4);
    p += __shfl_xor(p, 8);
    sc[n] = p;
  }
  float mx = sc[0];
#pragma unroll
  for (int n = 1; n < 20; ++n) mx = fmaxf(mx, sc[n]);
  const float CSC = 0.25505417705366035f;   // log2(e)/sqrt(32)
  float sum = 0.f;
#pragma unroll
  for (int n = 0; n < 20; ++n) { sc[n] = exp2f((sc[n] - mx) * CSC); sum += sc[n]; }
  float inv = 1.f / sum;

  float s0[4] = {0,0,0,0}, s1[4] = {0,0,0,0};
#pragma unroll
  for (int n = 0; n < 20; ++n) {
    const float* r = L + n * 128 + 4 * g;
    float4 a0 = *(const float4*)r;
    float4 a1 = *(const float4*)(r + 64);
    s0[0] += sc[n]*a0.x; s0[1] += sc[n]*a0.y; s0[2] += sc[n]*a0.z; s0[3] += sc[n]*a0.w;
    s1[0] += sc[n]*a1.x; s1[1] += sc[n]*a1.y; s1[2] += sc[n]*a1.z; s1[3] += sc[n]*a1.w;
  }
  shortv4 o0, o1;
#pragma unroll
  for (int j = 0; j < 4; ++j) { o0[j] = f2bf(s0[j] * inv); o1[j] = f2bf(s1[j] * inv); }
  short* sp = TS + (size_t)b * 512 + h * 128;
  *(shortv4*)(sp + 4 * g) = o0;
  *(shortv4*)(sp + 64 + 4 * g) = o1;
}

// ---------------------------------------------------------------------------
// K3: per 16-row tile per wave:
//   out_h = s_h @ Wv_h^T + bv  -> ovec[m][d*4+h]   (head interleave)
//   o1 = ovec @ Wo^T + bo      (kept in C-frags AND LDS)
//   u  = relu(o1 @ Wse1^T)     ; se = sigmoid(u @ Wse2^T) ; o2 = o1*se
//   gate = sigmoid(Wg.[x,o2]+bg) ; out = gate*o2 + (1-gate)*x
// LDS tiles bf16 stride 136 (35KB/block total, under 64KB static cap).
// ---------------------------------------------------------------------------
__global__ __launch_bounds__(256) void k_out(
    const float* __restrict__ x, const short* __restrict__ S,
    const short* __restrict__ wv, const short* __restrict__ wo,
    const short* __restrict__ ws1, const short* __restrict__ ws2,
    const float* __restrict__ bv, const float* __restrict__ bo,
    const float* __restrict__ wg, const float* __restrict__ bg,
    float* __restrict__ out)
{
  __shared__ short t_ov[4][16 * 136];   // ovec, reused for u
  __shared__ short t_o1[4][16 * 136];
  const int wid = threadIdx.x >> 6;
  const int lane = threadIdx.x & 63;
  const int g = lane & 15;
  const int q4 = lane >> 4;
  const int r0 = blockIdx.x * 64 + wid * 16;
  short* OV = t_ov[wid];
  short* O1 = t_o1[wid];

  // ---- Stage 0: out_h = s_h @ Wv_h^T + bv -> OV[m][d*4+h]
#pragma unroll
  for (int h = 0; h < 4; ++h) {
    short8 a[4];
#pragma unroll
    for (int ks = 0; ks < 4; ++ks)
      a[ks] = *(const short8*)(S + (size_t)(r0 + g) * 512 + h * 128 + ks * 32 + q4 * 8);
#pragma unroll
    for (int nt = 0; nt < 2; ++nt) {
      f32x4 acc = {0.f, 0.f, 0.f, 0.f};
#pragma unroll
      for (int ks = 0; ks < 4; ++ks) {
        short8 bfr = *(const short8*)(wv + (h * 32 + nt * 16 + g) * 128 + ks * 32 + q4 * 8);
        acc = __builtin_amdgcn_mfma_f32_16x16x32_bf16(a[ks], bfr, acc, 0, 0, 0);
      }
      int d = nt * 16 + g;
      float bias = bv[h * 32 + d];
#pragma unroll
      for (int i = 0; i < 4; ++i)
        OV[(q4 * 4 + i) * 136 + d * 4 + h] = f2bf(acc[i] + bias);
    }
  }
  __syncthreads();

  // ---- Stage 1: o1 = ovec @ Wo^T + bo
  short8 a1[4];
#pragma unroll
  for (int ks = 0; ks < 4; ++ks)
    a1[ks] = *(const short8*)(OV + g * 136 + ks * 32 + q4 * 8);
  f32x4 o1f[8];
#pragma unroll
  for (int nt = 0; nt < 8; ++nt) {
    f32x4 acc = {0.f, 0.f, 0.f, 0.f};
#pragma unroll
    for (int ks = 0; ks < 4; ++ks) {
      short8 bfr = *(const short8*)(wo + (nt * 16 + g) * 128 + ks * 32 + q4 * 8);
      acc = __builtin_amdgcn_mfma_f32_16x16x32_bf16(a1[ks], bfr, acc, 0, 0, 0);
    }
    float bias = bo[nt * 16 + g];
#pragma unroll
    for (int i = 0; i < 4; ++i) {
      acc[i] += bias;
      O1[(q4 * 4 + i) * 136 + nt * 16 + g] = f2bf(acc[i]);
    }
    o1f[nt] = acc;
  }
  __syncthreads();

  // ---- Stage 2: u = relu(o1 @ Wse1^T) -> OV[m][r], r<32
  short8 a2[4];
#pragma unroll
  for (int ks = 0; ks < 4; ++ks)
    a2[ks] = *(const short8*)(O1 + g * 136 + ks * 32 + q4 * 8);
#pragma unroll
  for (int nt = 0; nt < 2; ++nt) {
    f32x4 acc = {0.f, 0.f, 0.f, 0.f};
#pragma unroll
    for (int ks = 0; ks < 4; ++ks) {
      short8 bfr = *(const short8*)(ws1 + (nt * 16 + g) * 128 + ks * 32 + q4 * 8);
      acc = __builtin_amdgcn_mfma_f32_16x16x32_bf16(a2[ks], bfr, acc, 0, 0, 0);
    }
#pragma unroll
    for (int i = 0; i < 4; ++i)
      OV[(q4 * 4 + i) * 136 + nt * 16 + g] = f2bf(fmaxf(acc[i], 0.f));
  }
  __syncthreads();

  // ---- Stage 3: se_lin = u @ Wse2^T  (K=32, single k-step)
  short8 a3 = *(const short8*)(OV + g * 136 + q4 * 8);
  f32x4 sef[8];
#pragma unroll
  for (int nt = 0; nt < 8; ++nt) {
    short8 bfr = *(const short8*)(ws2 + (nt * 16 + g) * 32 + q4 * 8);
    f32x4 z4 = {0.f, 0.f, 0.f, 0.f};
    sef[nt] = __builtin_amdgcn_mfma_f32_16x16x32_bf16(a3, bfr, z4, 0, 0, 0);
  }

  // ---- Epilogue: SE gate, learned residual gate, final blend
  const float L2E = 1.4426950408889634f;
  float wg2[8];
#pragma unroll
  for (int nt = 0; nt < 8; ++nt) wg2[nt] = wg[128 + nt * 16 + g];
  float o2v[8][4];
  float zc[4] = {0.f, 0.f, 0.f, 0.f};
#pragma unroll
  for (int nt = 0; nt < 8; ++nt)
#pragma unroll
    for (int i = 0; i < 4; ++i) {
      float se = 1.f / (1.f + exp2f(-sef[nt][i] * L2E));
      float o2 = o1f[nt][i] * se;
      o2v[nt][i] = o2;
      zc[i] += wg2[nt] * o2;
    }
#pragma unroll
  for (int i = 0; i < 4; ++i) {
    zc[i] += __shfl_xor(zc[i], 1);
    zc[i] += __shfl_xor(zc[i], 2);
    zc[i] += __shfl_xor(zc[i], 4);
    zc[i] += __shfl_xor(zc[i], 8);
  }
  float wgx[8];
#pragma unroll
  for (int j = 0; j < 8; ++j) wgx[j] = wg[g * 8 + j];
  float bgv = bg[0];
  float gate[4];
#pragma unroll
  for (int i = 0; i < 4; ++i) {
    const float* xp = x + (size_t)(r0 + q4 * 4 + i) * 128 + g * 8;
    float4 x0 = *(const float4*)xp;
    float4 x1 = *(const float4*)(xp + 4);
    float px = wgx[0]*x0.x + wgx[1]*x0.y + wgx[2]*x0.z + wgx[3]*x0.w
             + wgx[4]*x1.x + wgx[5]*x1.y + wgx[6]*x1.z + wgx[7]*x1.w;
    px += __shfl_xor(px, 1);
    px += __shfl_xor(px, 2);
    px += __shfl_xor(px, 4);
    px += __shfl_xor(px, 8);
    float z = px + zc[i] + bgv;
    gate[i] = 1.f / (1.f + exp2f(-z * L2E));
  }
#pragma unroll
  for (int nt = 0; nt < 8; ++nt)
#pragma unroll
    for (int i = 0; i < 4; ++i) {
      size_t row = r0 + q4 * 4 + i;
      float xv = x[row * 128 + nt * 16 + g];
      out[row * 128 + nt * 16 + g] = xv + gate[i] * (o2v[nt][i] - xv);
    }
}

// ---------------------------------------------------------------------------
extern "C" void kernel_launch(void* const* d_in, const int* in_sizes, int n_in,
                              void* d_out, int out_size, void* d_ws, size_t ws_size,
                              hipStream_t stream)
{
  const float* x   = (const float*)d_in[0];
  const float* nb  = (const float*)d_in[1];
  const float* Wq  = (const float*)d_in[2];
  const float* bq  = (const float*)d_in[3];
  const float* Wk  = (const float*)d_in[4];
  // d_in[5] = bk: dropped (softmax shift-invariance)
  const float* Wv  = (const float*)d_in[6];
  const float* bv  = (const float*)d_in[7];
  const float* Wo  = (const float*)d_in[8];
  const float* bo  = (const float*)d_in[9];
  const float* Ws1 = (const float*)d_in[10];
  const float* Ws2 = (const float*)d_in[11];
  const float* wg  = (const float*)d_in[12];
  const float* bg  = (const float*)d_in[13];
  float* out = (float*)d_out;

  // Workspace layout: [TS: B*512 bf16 = 64MB][bf16 weights ~144KB]
  char* ws = (char*)d_ws;
  short* TS   = (short*)ws;
  short* wqb  = (short*)(ws + (size_t)67108864);
  short* wktb = wqb  + 16384;
  short* wvb  = wktb + 16384;
  short* wob  = wvb  + 16384;
  short* ws1b = wob  + 16384;
  short* ws2b = ws1b + 4096;

  k_prep<<<64, 256, 0, stream>>>(Wq, Wk, Wv, Wo, Ws1, Ws2,
                                 wqb, wktb, wvb, wob, ws1b, ws2b);
  k_qt  <<<1024, 256, 0, stream>>>(x, bq, wqb, wktb, TS);
  k_attn<<<16384, 256, 0, stream>>>(nb, TS);
  k_out <<<1024, 256, 0, stream>>>(x, TS, wvb, wob, ws1b, ws2b,
                                   bv, bo, wg, bg, out);
}

// Round 2
// 995.861 us; speedup vs baseline: 1.0086x; 1.0086x over previous
//
#include <hip/hip_runtime.h>
#include <hip/hip_bf16.h>
#include <stdint.h>

// Problem constants: B=65536, N=20, C=128, H=4, HD=32, OC=128
#define NROWS 65536

typedef short short8 __attribute__((ext_vector_type(8)));
typedef short shortv4 __attribute__((ext_vector_type(4)));
typedef float f32x4 __attribute__((ext_vector_type(4)));

__device__ __forceinline__ short f2bf(float f) {
  uint32_t u = __float_as_uint(f);
  u += 0x7FFFu + ((u >> 16) & 1u);   // round-to-nearest-even
  return (short)(u >> 16);
}
__device__ __forceinline__ float bf2f(short s) {
  return __uint_as_float(((uint32_t)(uint16_t)s) << 16);
}
__device__ __forceinline__ short8 pk8(float4 a, float4 b) {
  short8 r;
  r[0] = f2bf(a.x); r[1] = f2bf(a.y); r[2] = f2bf(a.z); r[3] = f2bf(a.w);
  r[4] = f2bf(b.x); r[5] = f2bf(b.y); r[6] = f2bf(b.z); r[7] = f2bf(b.w);
  return r;
}
// unpack 8 bf16 (as uint4) -> 8 fp32
__device__ __forceinline__ void unpack8(uint4 u, float* f) {
  f[0] = __uint_as_float(u.x << 16); f[1] = __uint_as_float(u.x & 0xFFFF0000u);
  f[2] = __uint_as_float(u.y << 16); f[3] = __uint_as_float(u.y & 0xFFFF0000u);
  f[4] = __uint_as_float(u.z << 16); f[5] = __uint_as_float(u.z & 0xFFFF0000u);
  f[6] = __uint_as_float(u.w << 16); f[7] = __uint_as_float(u.w & 0xFFFF0000u);
}

// ---------------------------------------------------------------------------
// K0: weight prep — bf16 casts, Wk transposed (wkt[c][d] = Wk[d][c]) so K1's
// B-fragments are 16B-contiguous loads.
// ---------------------------------------------------------------------------
__global__ __launch_bounds__(256) void k_prep(
    const float* __restrict__ Wq, const float* __restrict__ Wk,
    const float* __restrict__ Wv, const float* __restrict__ Wo,
    const float* __restrict__ Ws1, const float* __restrict__ Ws2,
    short* __restrict__ wq, short* __restrict__ wkt, short* __restrict__ wv,
    short* __restrict__ wo, short* __restrict__ ws1, short* __restrict__ ws2)
{
  int idx = blockIdx.x * 256 + threadIdx.x;
  int stride = gridDim.x * 256;
  for (int i = idx; i < 16384; i += stride) {
    wq[i] = f2bf(Wq[i]);
    wv[i] = f2bf(Wv[i]);
    wo[i] = f2bf(Wo[i]);
    int c = i >> 7, d = i & 127;
    wkt[i] = f2bf(Wk[d * 128 + c]);       // wkt[c*128+d] = Wk[d][c]
  }
  for (int i = idx; i < 4096; i += stride) {
    ws1[i] = f2bf(Ws1[i]);
    ws2[i] = f2bf(Ws2[i]);
  }
}

// ---------------------------------------------------------------------------
// K1: per 16-row tile (1 tile/wave, 4 waves/block):
//   Q = X @ Wq^T + bq          (MFMA, 8 ntiles x 4 ksteps)
//   T_h = Q_h @ Wk_h           (MFMA, K=32, 4 heads x 8 ntiles)
// bk dropped (softmax-shift invariant).
// ---------------------------------------------------------------------------
__global__ __launch_bounds__(256) void k_qt(
    const float* __restrict__ x, const float* __restrict__ bq,
    const short* __restrict__ wq, const short* __restrict__ wkt,
    short* __restrict__ T)
{
  __shared__ short qtile[4][16 * 136];
  const int wid = threadIdx.x >> 6;
  const int lane = threadIdx.x & 63;
  const int g = lane & 15;
  const int q4 = lane >> 4;
  const int r0 = blockIdx.x * 64 + wid * 16;
  short* Q = qtile[wid];

  // A-fragments from x (fp32 -> bf16): A[m=g][k=ks*32+q4*8+j]
  short8 af[4];
#pragma unroll
  for (int ks = 0; ks < 4; ++ks) {
    const float* p = x + (size_t)(r0 + g) * 128 + ks * 32 + q4 * 8;
    af[ks] = pk8(*(const float4*)p, *(const float4*)(p + 4));
  }
  // Q = X @ Wq^T + bq  -> LDS (bf16)
#pragma unroll
  for (int nt = 0; nt < 8; ++nt) {
    f32x4 acc = {0.f, 0.f, 0.f, 0.f};
#pragma unroll
    for (int ks = 0; ks < 4; ++ks) {
      short8 bfr = *(const short8*)(wq + (nt * 16 + g) * 128 + ks * 32 + q4 * 8);
      acc = __builtin_amdgcn_mfma_f32_16x16x32_bf16(af[ks], bfr, acc, 0, 0, 0);
    }
    float bias = bq[nt * 16 + g];
#pragma unroll
    for (int i = 0; i < 4; ++i)
      Q[(q4 * 4 + i) * 136 + nt * 16 + g] = f2bf(acc[i] + bias);
  }
  __syncthreads();

  // T_h = Q_h @ Wk_h  (K=32, single MFMA k-step per (h,nt))
#pragma unroll
  for (int h = 0; h < 4; ++h) {
    short8 a = *(const short8*)(Q + g * 136 + h * 32 + q4 * 8);
#pragma unroll
    for (int nt = 0; nt < 8; ++nt) {
      short8 bfr = *(const short8*)(wkt + (nt * 16 + g) * 128 + h * 32 + q4 * 8);
      f32x4 acc = {0.f, 0.f, 0.f, 0.f};
      acc = __builtin_amdgcn_mfma_f32_16x16x32_bf16(a, bfr, acc, 0, 0, 0);
#pragma unroll
      for (int i = 0; i < 4; ++i)
        T[(size_t)(r0 + q4 * 4 + i) * 512 + h * 128 + nt * 16 + g] = f2bf(acc[i]);
    }
  }
}

// ---------------------------------------------------------------------------
// K2: attention core. One wave per row b; private LDS region per wave (no
// barriers). 16-lane group per head h=lane>>4; lane g owns channels
// 8g..8g+7 (contiguous, 16B ops everywhere). Neighbors staged as bf16
// (21.25 KB/block -> 7 blocks/CU, 28 waves/CU).
//   scores[h][n] = t_h . nb[n]    (8-ch dot + 4-step butterfly)
//   softmax over n (1/sqrt(32) folded into exp2)
//   s_h = sum_n attn[n]*nb[n]     (normalized; bv applied in K3)
// S (bf16) overwrites T in-place — same wave reads T before writing S.
// ---------------------------------------------------------------------------
__global__ __launch_bounds__(256) void k_attn(
    const float* __restrict__ nb, short* __restrict__ TS)
{
  __shared__ short lnb[4][20 * 136];     // bf16 neighbors, per-wave region
  const int wid = threadIdx.x >> 6;
  const int lane = threadIdx.x & 63;
  const int g = lane & 15;
  const int h = lane >> 4;
  const int b = blockIdx.x * 4 + wid;
  short* L = lnb[wid];

  // stage fp32 -> bf16: lane covers row (j*4+h), channels 8g..8g+7
  const float* src = nb + (size_t)b * 2560;
#pragma unroll
  for (int j = 0; j < 5; ++j) {
    int n = j * 4 + h;
    const float* p = src + n * 128 + g * 8;
    *(short8*)(L + n * 136 + g * 8) = pk8(*(const float4*)p, *(const float4*)(p + 4));
  }

  // t for this head (channels 8g..8g+7)
  float t[8];
  unpack8(*(const uint4*)(TS + (size_t)b * 512 + h * 128 + g * 8), t);

  float sc[20];
#pragma unroll
  for (int n = 0; n < 20; ++n) {
    float c[8];
    unpack8(*(const uint4*)(L + n * 136 + g * 8), c);
    float p = t[0]*c[0] + t[1]*c[1] + t[2]*c[2] + t[3]*c[3]
            + t[4]*c[4] + t[5]*c[5] + t[6]*c[6] + t[7]*c[7];
    p += __shfl_xor(p, 1);
    p += __shfl_xor(p, 2);
    p += __shfl_xor(p, 4);
    p += __shfl_xor(p, 8);
    sc[n] = p;
  }
  float mx = sc[0];
#pragma unroll
  for (int n = 1; n < 20; ++n) mx = fmaxf(mx, sc[n]);
  const float CSC = 0.25505417705366035f;   // log2(e)/sqrt(32)
  float sum = 0.f;
#pragma unroll
  for (int n = 0; n < 20; ++n) { sc[n] = exp2f((sc[n] - mx) * CSC); sum += sc[n]; }
  float inv = 1.f / sum;

  float s[8] = {0, 0, 0, 0, 0, 0, 0, 0};
#pragma unroll
  for (int n = 0; n < 20; ++n) {
    float c[8];
    unpack8(*(const uint4*)(L + n * 136 + g * 8), c);
#pragma unroll
    for (int k2 = 0; k2 < 8; ++k2) s[k2] += sc[n] * c[k2];
  }
  short8 o;
#pragma unroll
  for (int k2 = 0; k2 < 8; ++k2) o[k2] = f2bf(s[k2] * inv);
  *(short8*)(TS + (size_t)b * 512 + h * 128 + g * 8) = o;
}

// ---------------------------------------------------------------------------
// K3: per 16-row tile per wave:
//   out_h = s_h @ Wv_h^T + bv  -> ovec[m][d*4+h]   (head interleave)
//   o1 = ovec @ Wo^T + bo      (kept in C-frags AND LDS)
//   u  = relu(o1 @ Wse1^T)     ; se = sigmoid(u @ Wse2^T) ; o2 = o1*se
//   gate = sigmoid(Wg.[x,o2]+bg) ; out = gate*o2 + (1-gate)*x
// ---------------------------------------------------------------------------
__global__ __launch_bounds__(256) void k_out(
    const float* __restrict__ x, const short* __restrict__ S,
    const short* __restrict__ wv, const short* __restrict__ wo,
    const short* __restrict__ ws1, const short* __restrict__ ws2,
    const float* __restrict__ bv, const float* __restrict__ bo,
    const float* __restrict__ wg, const float* __restrict__ bg,
    float* __restrict__ out)
{
  __shared__ short t_ov[4][16 * 136];   // ovec, reused for u
  __shared__ short t_o1[4][16 * 136];
  const int wid = threadIdx.x >> 6;
  const int lane = threadIdx.x & 63;
  const int g = lane & 15;
  const int q4 = lane >> 4;
  const int r0 = blockIdx.x * 64 + wid * 16;
  short* OV = t_ov[wid];
  short* O1 = t_o1[wid];

  // ---- Stage 0: out_h = s_h @ Wv_h^T + bv -> OV[m][d*4+h]
#pragma unroll
  for (int h = 0; h < 4; ++h) {
    short8 a[4];
#pragma unroll
    for (int ks = 0; ks < 4; ++ks)
      a[ks] = *(const short8*)(S + (size_t)(r0 + g) * 512 + h * 128 + ks * 32 + q4 * 8);
#pragma unroll
    for (int nt = 0; nt < 2; ++nt) {
      f32x4 acc = {0.f, 0.f, 0.f, 0.f};
#pragma unroll
      for (int ks = 0; ks < 4; ++ks) {
        short8 bfr = *(const short8*)(wv + (h * 32 + nt * 16 + g) * 128 + ks * 32 + q4 * 8);
        acc = __builtin_amdgcn_mfma_f32_16x16x32_bf16(a[ks], bfr, acc, 0, 0, 0);
      }
      int d = nt * 16 + g;
      float bias = bv[h * 32 + d];
#pragma unroll
      for (int i = 0; i < 4; ++i)
        OV[(q4 * 4 + i) * 136 + d * 4 + h] = f2bf(acc[i] + bias);
    }
  }
  __syncthreads();

  // ---- Stage 1: o1 = ovec @ Wo^T + bo
  short8 a1[4];
#pragma unroll
  for (int ks = 0; ks < 4; ++ks)
    a1[ks] = *(const short8*)(OV + g * 136 + ks * 32 + q4 * 8);
  f32x4 o1f[8];
#pragma unroll
  for (int nt = 0; nt < 8; ++nt) {
    f32x4 acc = {0.f, 0.f, 0.f, 0.f};
#pragma unroll
    for (int ks = 0; ks < 4; ++ks) {
      short8 bfr = *(const short8*)(wo + (nt * 16 + g) * 128 + ks * 32 + q4 * 8);
      acc = __builtin_amdgcn_mfma_f32_16x16x32_bf16(a1[ks], bfr, acc, 0, 0, 0);
    }
    float bias = bo[nt * 16 + g];
#pragma unroll
    for (int i = 0; i < 4; ++i) {
      acc[i] += bias;
      O1[(q4 * 4 + i) * 136 + nt * 16 + g] = f2bf(acc[i]);
    }
    o1f[nt] = acc;
  }
  __syncthreads();

  // ---- Stage 2: u = relu(o1 @ Wse1^T) -> OV[m][r], r<32
  short8 a2[4];
#pragma unroll
  for (int ks = 0; ks < 4; ++ks)
    a2[ks] = *(const short8*)(O1 + g * 136 + ks * 32 + q4 * 8);
#pragma unroll
  for (int nt = 0; nt < 2; ++nt) {
    f32x4 acc = {0.f, 0.f, 0.f, 0.f};
#pragma unroll
    for (int ks = 0; ks < 4; ++ks) {
      short8 bfr = *(const short8*)(ws1 + (nt * 16 + g) * 128 + ks * 32 + q4 * 8);
      acc = __builtin_amdgcn_mfma_f32_16x16x32_bf16(a2[ks], bfr, acc, 0, 0, 0);
    }
#pragma unroll
    for (int i = 0; i < 4; ++i)
      OV[(q4 * 4 + i) * 136 + nt * 16 + g] = f2bf(fmaxf(acc[i], 0.f));
  }
  __syncthreads();

  // ---- Stage 3: se_lin = u @ Wse2^T  (K=32, single k-step)
  short8 a3 = *(const short8*)(OV + g * 136 + q4 * 8);
  f32x4 sef[8];
#pragma unroll
  for (int nt = 0; nt < 8; ++nt) {
    short8 bfr = *(const short8*)(ws2 + (nt * 16 + g) * 32 + q4 * 8);
    f32x4 z4 = {0.f, 0.f, 0.f, 0.f};
    sef[nt] = __builtin_amdgcn_mfma_f32_16x16x32_bf16(a3, bfr, z4, 0, 0, 0);
  }

  // ---- Epilogue: SE gate, learned residual gate, final blend
  const float L2E = 1.4426950408889634f;
  float wg2[8];
#pragma unroll
  for (int nt = 0; nt < 8; ++nt) wg2[nt] = wg[128 + nt * 16 + g];
  float o2v[8][4];
  float zc[4] = {0.f, 0.f, 0.f, 0.f};
#pragma unroll
  for (int nt = 0; nt < 8; ++nt)
#pragma unroll
    for (int i = 0; i < 4; ++i) {
      float se = 1.f / (1.f + exp2f(-sef[nt][i] * L2E));
      float o2 = o1f[nt][i] * se;
      o2v[nt][i] = o2;
      zc[i] += wg2[nt] * o2;
    }
#pragma unroll
  for (int i = 0; i < 4; ++i) {
    zc[i] += __shfl_xor(zc[i], 1);
    zc[i] += __shfl_xor(zc[i], 2);
    zc[i] += __shfl_xor(zc[i], 4);
    zc[i] += __shfl_xor(zc[i], 8);
  }
  float wgx[8];
#pragma unroll
  for (int j = 0; j < 8; ++j) wgx[j] = wg[g * 8 + j];
  float bgv = bg[0];
  float gate[4];
#pragma unroll
  for (int i = 0; i < 4; ++i) {
    const float* xp = x + (size_t)(r0 + q4 * 4 + i) * 128 + g * 8;
    float4 x0 = *(const float4*)xp;
    float4 x1 = *(const float4*)(xp + 4);
    float px = wgx[0]*x0.x + wgx[1]*x0.y + wgx[2]*x0.z + wgx[3]*x0.w
             + wgx[4]*x1.x + wgx[5]*x1.y + wgx[6]*x1.z + wgx[7]*x1.w;
    px += __shfl_xor(px, 1);
    px += __shfl_xor(px, 2);
    px += __shfl_xor(px, 4);
    px += __shfl_xor(px, 8);
    float z = px + zc[i] + bgv;
    gate[i] = 1.f / (1.f + exp2f(-z * L2E));
  }
#pragma unroll
  for (int nt = 0; nt < 8; ++nt)
#pragma unroll
    for (int i = 0; i < 4; ++i) {
      size_t row = r0 + q4 * 4 + i;
      float xv = x[row * 128 + nt * 16 + g];
      out[row * 128 + nt * 16 + g] = xv + gate[i] * (o2v[nt][i] - xv);
    }
}

// ---------------------------------------------------------------------------
extern "C" void kernel_launch(void* const* d_in, const int* in_sizes, int n_in,
                              void* d_out, int out_size, void* d_ws, size_t ws_size,
                              hipStream_t stream)
{
  const float* x   = (const float*)d_in[0];
  const float* nb  = (const float*)d_in[1];
  const float* Wq  = (const float*)d_in[2];
  const float* bq  = (const float*)d_in[3];
  const float* Wk  = (const float*)d_in[4];
  // d_in[5] = bk: dropped (softmax shift-invariance)
  const float* Wv  = (const float*)d_in[6];
  const float* bv  = (const float*)d_in[7];
  const float* Wo  = (const float*)d_in[8];
  const float* bo  = (const float*)d_in[9];
  const float* Ws1 = (const float*)d_in[10];
  const float* Ws2 = (const float*)d_in[11];
  const float* wg  = (const float*)d_in[12];
  const float* bg  = (const float*)d_in[13];
  float* out = (float*)d_out;

  // Workspace layout: [TS: B*512 bf16 = 64MB][bf16 weights ~144KB]
  char* ws = (char*)d_ws;
  short* TS   = (short*)ws;
  short* wqb  = (short*)(ws + (size_t)67108864);
  short* wktb = wqb  + 16384;
  short* wvb  = wktb + 16384;
  short* wob  = wvb  + 16384;
  short* ws1b = wob  + 16384;
  short* ws2b = ws1b + 4096;

  k_prep<<<64, 256, 0, stream>>>(Wq, Wk, Wv, Wo, Ws1, Ws2,
                                 wqb, wktb, wvb, wob, ws1b, ws2b);
  k_qt  <<<1024, 256, 0, stream>>>(x, bq, wqb, wktb, TS);
  k_attn<<<16384, 256, 0, stream>>>(nb, TS);
  k_out <<<1024, 256, 0, stream>>>(x, TS, wvb, wob, ws1b, ws2b,
                                   bv, bo, wg, bg, out);
}